// Round 2
// 296.683 us; speedup vs baseline: 1.0177x; 1.0177x over previous
//
#include <hip/hip_runtime.h>

// BBoxGenerator: (256,1,512,512) fp32 mask -> (256,4) boxes [x0,y0,x1,y1].
// R4 (resubmit after infra failure): single fused kernel. One block per
// image (256 blocks x 256 threads), ONE WAVE PER PHASE (0:ymin 1:ymax
// 2:xmin 3:xmax). Each wave early-exit scans with wave-local reductions
// only (__any / shfl min) -- no block barriers in the probe loop (R3 paid
// 2 __syncthreads per probe), no workspace round-trip, no second launch.
// Final combine + expand epilogue behind a single __syncthreads, thread 0
// writes the float4 box.
//
// Timed-window note: harness re-poison fills (1 GiB @ ~6.6 TB/s, ~160 us
// each) dominate dur_us; our controllable slice is ~5%.

constexpr int H = 512;
constexpr int W = 512;
constexpr int BIG = 1 << 29;   // sentinel: "nothing found"

__device__ __forceinline__ int wave_min_bcast(int v) {
    #pragma unroll
    for (int off = 32; off > 0; off >>= 1) v = min(v, __shfl_down(v, off));
    return __shfl(v, 0);       // broadcast lane 0's min to all lanes
}

__global__ __launch_bounds__(256)
void bbox_kernel(const float* __restrict__ mask, float* __restrict__ out) {
    const int b = blockIdx.x;
    const float4* __restrict__ img =
        reinterpret_cast<const float4*>(mask) + (size_t)b * (H * W / 4);
    const int t = threadIdx.x;
    const int wave = t >> 6;
    const int lane = t & 63;
    __shared__ int s_res[4];

    int result = BIG;

    if (wave < 2) {
        // y scan: one full row per probe. lane reads float4 cols {lane, lane+64}
        // (coalesced, 1 KB/probe). Early exit via wave ballot -- exact: rows
        // are visited in order, first row with any fg is the extremum.
        for (int i = 0; i < H; ++i) {
            const int r = (wave == 0) ? i : (H - 1 - i);
            const float4 a = img[(r << 7) + lane];
            const float4 c = img[(r << 7) + 64 + lane];
            const bool fg = (a.x > 0.5f) | (a.y > 0.5f) | (a.z > 0.5f) | (a.w > 0.5f) |
                            (c.x > 0.5f) | (c.y > 0.5f) | (c.z > 0.5f) | (c.w > 0.5f);
            if (__any(fg)) { result = (wave == 0) ? r : -r; break; }
        }
    } else {
        // x scan: one float4-wide column strip per probe, all 512 rows
        // (lane covers rows lane+64k, 8 independent loads issued together).
        // If the strip contains fg, the strip-wide min col is exact (all
        // earlier strips were empty and this strip is fully scanned).
        for (int i = 0; i < W / 4; ++i) {
            const int ss = (wave == 2) ? i : (W / 4 - 1 - i);
            const int c = ss << 2;
            int key = BIG;
            #pragma unroll
            for (int k = 0; k < 8; ++k) {
                const int r = lane + (k << 6);
                const float4 v = img[(r << 7) + ss];
                int kk = BIG;
                if (wave == 2) {           // leftmost fg col in this float4
                    if (v.w > 0.5f) kk = c + 3;
                    if (v.z > 0.5f) kk = c + 2;
                    if (v.y > 0.5f) kk = c + 1;
                    if (v.x > 0.5f) kk = c;
                } else {                   // rightmost, negated for min-reduce
                    if (v.x > 0.5f) kk = -c;
                    if (v.y > 0.5f) kk = -(c + 1);
                    if (v.z > 0.5f) kk = -(c + 2);
                    if (v.w > 0.5f) kk = -(c + 3);
                }
                key = min(key, kk);
            }
            key = wave_min_bcast(key);
            if (key < BIG) { result = key; break; }
        }
    }

    if (lane == 0) s_res[wave] = result;
    __syncthreads();

    if (t == 0) {
        const int ymin  = s_res[0];
        const int nymax = s_res[1];
        const int xmin  = s_res[2];
        const int nxmax = s_res[3];
        float x0, y0, x1, y1;
        if (ymin >= BIG) {
            x0 = 0.25f; y0 = 0.25f; x1 = 0.75f; y1 = 0.75f;
        } else {
            const int ymax = -nymax, xmax = -nxmax;
            y0 = (float)ymin * (1.0f / H);
            y1 = (float)ymax * (1.0f / H);
            x0 = (float)xmin * (1.0f / W);
            x1 = (float)xmax * (1.0f / W);
            const float s = 0.05f;
            if (x1 - x0 < s) {
                const float c = (x0 + x1) * 0.5f;
                x0 = fmaxf(0.0f, c - s * 0.5f);
                x1 = fminf(1.0f, c + s * 0.5f);
            }
            if (y1 - y0 < s) {
                const float c = (y0 + y1) * 0.5f;
                y0 = fmaxf(0.0f, c - s * 0.5f);
                y1 = fminf(1.0f, c + s * 0.5f);
            }
        }
        reinterpret_cast<float4*>(out)[b] = make_float4(x0, y0, x1, y1);
    }
}

extern "C" void kernel_launch(void* const* d_in, const int* in_sizes, int n_in,
                              void* d_out, int out_size, void* d_ws, size_t ws_size,
                              hipStream_t stream) {
    const float* mask = (const float*)d_in[0];
    float* out = (float*)d_out;
    const int B = in_sizes[0] / (H * W);  // 256
    bbox_kernel<<<B, 256, 0, stream>>>(mask, out);
}